// Round 1
// baseline (686.987 us; speedup 1.0000x reference)
//
#include <hip/hip_runtime.h>
#include <hip/hip_fp16.h>

// VGAE: h = relu(GC(x,W1)); agg2 = norm-agg(h); mean=agg2@W2+b2; ls=agg2@W3+b3;
// z = mean + noise*exp(ls); out = sigmoid(z @ z^T)
// GC(x,W) = (segsum((x*rsqrt(deg_out))[src] -> dst) * rsqrt(deg_in)) @ W + b
// Reordering (linear): do @W first for layer 1; share aggregation for W2/W3.

#define NN 10000
#define NE 320000
#define FD 512
#define H1 256
#define H2 128

typedef _Float16 half8 __attribute__((ext_vector_type(8)));
typedef float f32x4 __attribute__((ext_vector_type(4)));

__device__ __forceinline__ void acc4(float4& a, const float4 v) {
    a.x += v.x; a.y += v.y; a.z += v.z; a.w += v.w;
}

__global__ void k_zero(int* __restrict__ p, int n) {
    int i = blockIdx.x * blockDim.x + threadIdx.x;
    if (i < n) p[i] = 0;
}

__global__ void k_count(const int* __restrict__ src, const int* __restrict__ dst,
                        int* __restrict__ co, int* __restrict__ ci) {
    int e = blockIdx.x * blockDim.x + threadIdx.x;
    if (e < NE) {
        atomicAdd(&co[src[e]], 1);
        atomicAdd(&ci[dst[e]], 1);
    }
}

// One block: exclusive scan of in-degrees -> row_ptr; rsqrt of clamped degrees; zero cursors.
__global__ __launch_bounds__(1024) void k_scan(const int* __restrict__ ci, const int* __restrict__ co,
                                               int* __restrict__ row_ptr, int* __restrict__ cursor,
                                               float* __restrict__ rs_in, float* __restrict__ rs_out) {
    __shared__ int sm[1024];
    int tid = threadIdx.x;
    const int CH = (NN + 1023) / 1024;  // 10
    int base = tid * CH;
    int local[CH];
    int s = 0;
    #pragma unroll
    for (int i = 0; i < CH; ++i) {
        int idx = base + i;
        local[i] = s;
        if (idx < NN) s += ci[idx];
    }
    sm[tid] = s;
    __syncthreads();
    for (int off = 1; off < 1024; off <<= 1) {
        int v = (tid >= off) ? sm[tid - off] : 0;
        __syncthreads();
        sm[tid] += v;
        __syncthreads();
    }
    int excl = sm[tid] - s;
    #pragma unroll
    for (int i = 0; i < CH; ++i) {
        int idx = base + i;
        if (idx < NN) row_ptr[idx] = excl + local[i];
    }
    if (tid == 1023) row_ptr[NN] = sm[1023];
    for (int i = tid; i < NN; i += 1024) {
        int a = ci[i], b = co[i];
        rs_in[i]  = rsqrtf((float)(a > 1 ? a : 1));
        rs_out[i] = rsqrtf((float)(b > 1 ? b : 1));
        cursor[i] = 0;
    }
}

__global__ void k_bucket(const int* __restrict__ src, const int* __restrict__ dst,
                         const int* __restrict__ row_ptr, int* __restrict__ cursor,
                         int* __restrict__ esrc) {
    int e = blockIdx.x * blockDim.x + threadIdx.x;
    if (e < NE) {
        int d = dst[e];
        int p = row_ptr[d] + atomicAdd(&cursor[d], 1);
        esrc[p] = src[e];
    }
}

// C[M][N] = (ascale ? diag(ascale) : I) * A @ B + bias, B/bias split at column nsplit (B0|B1).
// BM=64,BN=64,BK=16, 256 threads, 4x4 per thread.
__global__ __launch_bounds__(256) void k_gemm(
    const float* __restrict__ A, int lda, int M, int K,
    const float* __restrict__ B0, const float* __restrict__ B1, int ldb, int nsplit,
    const float* __restrict__ bias0, const float* __restrict__ bias1,
    const float* __restrict__ ascale, float* __restrict__ C, int ldc) {
    __shared__ __align__(16) float As[16][64];  // [k][m]
    __shared__ __align__(16) float Bs[16][64];  // [k][n]
    int tid = threadIdx.x;
    int bm = blockIdx.x * 64;
    int bn = blockIdx.y * 64;
    const float* Bp; const float* bp; int bcol;
    if (bn < nsplit) { Bp = B0; bp = bias0; bcol = bn; }
    else             { Bp = B1; bp = bias1; bcol = bn - nsplit; }
    int tm = tid >> 4, tn = tid & 15;
    float acc[4][4] = {};
    int arow = tid >> 2;   // 0..63
    int akq  = tid & 3;    // which float4 of the 16-k slice
    int brow = tid >> 4;   // 0..15
    int bq   = tid & 15;   // float4 along n
    int garow = bm + arow;
    const float* Aptr = (garow < M) ? (A + (size_t)garow * lda) : nullptr;
    float ascl = (ascale && garow < M) ? ascale[garow] : 1.0f;
    for (int k0 = 0; k0 < K; k0 += 16) {
        float4 av = {0.f, 0.f, 0.f, 0.f};
        if (Aptr) av = *(const float4*)(Aptr + k0 + akq * 4);
        av.x *= ascl; av.y *= ascl; av.z *= ascl; av.w *= ascl;
        float4 bv = *(const float4*)(Bp + (size_t)(k0 + brow) * ldb + bcol + bq * 4);
        __syncthreads();
        As[akq * 4 + 0][arow] = av.x;
        As[akq * 4 + 1][arow] = av.y;
        As[akq * 4 + 2][arow] = av.z;
        As[akq * 4 + 3][arow] = av.w;
        *(float4*)&Bs[brow][bq * 4] = bv;
        __syncthreads();
        #pragma unroll
        for (int kk = 0; kk < 16; ++kk) {
            float4 a = *(const float4*)&As[kk][tm * 4];
            float4 b = *(const float4*)&Bs[kk][tn * 4];
            float ar[4] = {a.x, a.y, a.z, a.w};
            float br[4] = {b.x, b.y, b.z, b.w};
            #pragma unroll
            for (int i = 0; i < 4; ++i)
                #pragma unroll
                for (int j = 0; j < 4; ++j)
                    acc[i][j] += ar[i] * br[j];
        }
    }
    float bvv[4];
    #pragma unroll
    for (int j = 0; j < 4; ++j) bvv[j] = bp ? bp[bcol + tn * 4 + j] : 0.0f;
    #pragma unroll
    for (int i = 0; i < 4; ++i) {
        int row = bm + tm * 4 + i;
        if (row < M) {
            float4 v;
            v.x = acc[i][0] + bvv[0];
            v.y = acc[i][1] + bvv[1];
            v.z = acc[i][2] + bvv[2];
            v.w = acc[i][3] + bvv[3];
            *(float4*)(C + (size_t)row * ldc + bn + tn * 4) = v;
        }
    }
}

// One wave per node: sum rows in[esrc[e]][0..255], scale, (opt) +bias,relu,*rs_out.
template <bool FIRST>
__global__ __launch_bounds__(256) void k_agg(const float* __restrict__ in, float* __restrict__ out,
                                             const int* __restrict__ esrc, const int* __restrict__ row_ptr,
                                             const float* __restrict__ rs_in, const float* __restrict__ rs_out,
                                             const float* __restrict__ bias) {
    int node = (blockIdx.x * blockDim.x + threadIdx.x) >> 6;
    int lane = threadIdx.x & 63;
    if (node >= NN) return;
    int beg = row_ptr[node], end = row_ptr[node + 1];
    float4 acc = {0.f, 0.f, 0.f, 0.f};
    int e = beg;
    for (; e + 4 <= end; e += 4) {
        int s0 = esrc[e + 0], s1 = esrc[e + 1], s2 = esrc[e + 2], s3 = esrc[e + 3];
        float4 v0 = ((const float4*)(in + (size_t)s0 * H1))[lane];
        float4 v1 = ((const float4*)(in + (size_t)s1 * H1))[lane];
        float4 v2 = ((const float4*)(in + (size_t)s2 * H1))[lane];
        float4 v3 = ((const float4*)(in + (size_t)s3 * H1))[lane];
        acc4(acc, v0); acc4(acc, v1); acc4(acc, v2); acc4(acc, v3);
    }
    for (; e < end; ++e) {
        float4 v0 = ((const float4*)(in + (size_t)esrc[e] * H1))[lane];
        acc4(acc, v0);
    }
    float si = rs_in[node];
    float4 r;
    r.x = acc.x * si; r.y = acc.y * si; r.z = acc.z * si; r.w = acc.w * si;
    if (FIRST) {
        float4 bb = ((const float4*)bias)[lane];
        float so = rs_out[node];
        r.x = fmaxf(r.x + bb.x, 0.f) * so;
        r.y = fmaxf(r.y + bb.y, 0.f) * so;
        r.z = fmaxf(r.z + bb.z, 0.f) * so;
        r.w = fmaxf(r.w + bb.w, 0.f) * so;
    }
    ((float4*)(out + (size_t)node * H1))[lane] = r;
}

// z = mean + noise*exp(log_std), cast fp16 (fp16 not bf16: 2^-11 rounding keeps
// worst-case sigmoid error ~0.007 << 0.02 threshold)
__global__ void k_z(const float* __restrict__ ml, const float* __restrict__ noise,
                    _Float16* __restrict__ z) {
    int i = blockIdx.x * blockDim.x + threadIdx.x;
    if (i < NN * H2) {
        int r = i >> 7, c = i & 127;
        float mean = ml[(size_t)r * 256 + c];
        float ls   = ml[(size_t)r * 256 + 128 + c];
        z[i] = (_Float16)(mean + noise[i] * __expf(ls));
    }
}

// out = sigmoid(Z @ Z^T). 128x128 tile/block (4 waves, 64x64 each), K=128 staged 2x64 in LDS.
// mfma_f32_16x16x32_f16: A[m=lane&15][k=quad*8+j]; C: col=lane&15, row=quad*4+reg.
__global__ __launch_bounds__(256) void k_decoder(const _Float16* __restrict__ Z, float* __restrict__ out) {
    __shared__ __align__(16) _Float16 As[128][72];  // stride 72 halves = 144 B (16B-mult, bank-safe)
    __shared__ __align__(16) _Float16 Bs[128][72];
    int tid = threadIdx.x;
    int lane = tid & 63;
    int w = tid >> 6;
    int wrow = (w >> 1) * 64;
    int wcol = (w & 1) * 64;
    int rowBase = blockIdx.y * 128;
    int colBase = blockIdx.x * 128;
    f32x4 acc[4][4] = {};
    for (int s = 0; s < 2; ++s) {
        __syncthreads();
        #pragma unroll
        for (int i = 0; i < 4; ++i) {
            int lin = i * 256 + tid;       // 0..1023 chunk id
            int r = lin >> 3, c = lin & 7; // 8 chunks of 8 halves per row
            int4 v = {0, 0, 0, 0};
            int gr = rowBase + r;
            if (gr < NN) v = *(const int4*)(Z + (size_t)gr * H2 + s * 64 + c * 8);
            *(int4*)&As[r][c * 8] = v;
            int4 u = {0, 0, 0, 0};
            int gc = colBase + r;
            if (gc < NN) u = *(const int4*)(Z + (size_t)gc * H2 + s * 64 + c * 8);
            *(int4*)&Bs[r][c * 8] = u;
        }
        __syncthreads();
        #pragma unroll
        for (int kk = 0; kk < 2; ++kk) {
            int kof = kk * 32 + ((lane >> 4) << 3);
            half8 a[4], b[4];
            #pragma unroll
            for (int f = 0; f < 4; ++f) a[f] = *(const half8*)&As[wrow + f * 16 + (lane & 15)][kof];
            #pragma unroll
            for (int f = 0; f < 4; ++f) b[f] = *(const half8*)&Bs[wcol + f * 16 + (lane & 15)][kof];
            #pragma unroll
            for (int i = 0; i < 4; ++i)
                #pragma unroll
                for (int j = 0; j < 4; ++j)
                    acc[i][j] = __builtin_amdgcn_mfma_f32_16x16x32_f16(a[i], b[j], acc[i][j], 0, 0, 0);
        }
    }
    #pragma unroll
    for (int i = 0; i < 4; ++i) {
        int row0 = rowBase + wrow + i * 16 + ((lane >> 4) << 2);
        #pragma unroll
        for (int j = 0; j < 4; ++j) {
            int col = colBase + wcol + j * 16 + (lane & 15);
            if (col < NN) {
                #pragma unroll
                for (int r = 0; r < 4; ++r) {
                    int row = row0 + r;
                    if (row < NN) {
                        float x = acc[i][j][r];
                        float sg = 1.0f / (1.0f + __expf(-x));
                        __builtin_nontemporal_store(sg, out + (size_t)row * NN + col);
                    }
                }
            }
        }
    }
}

extern "C" void kernel_launch(void* const* d_in, const int* in_sizes, int n_in,
                              void* d_out, int out_size, void* d_ws, size_t ws_size,
                              hipStream_t stream) {
    const float* features = (const float*)d_in[0];
    const int*   src      = (const int*)d_in[1];
    const int*   dst      = (const int*)d_in[2];
    const float* noise    = (const float*)d_in[3];
    const float* W1 = (const float*)d_in[4];
    const float* b1 = (const float*)d_in[5];
    const float* W2 = (const float*)d_in[6];
    const float* b2 = (const float*)d_in[7];
    const float* W3 = (const float*)d_in[8];
    const float* b3 = (const float*)d_in[9];
    float* out = (float*)d_out;
    (void)in_sizes; (void)n_in; (void)out_size; (void)ws_size;

    char* ws = (char*)d_ws;
    size_t off = 0;
    auto alloc = [&](size_t bytes) -> void* {
        void* p = ws + off;
        off += (bytes + 255) & ~(size_t)255;
        return p;
    };
    int* degc_out = (int*)alloc(NN * sizeof(int));
    int* degc_in  = (int*)alloc(NN * sizeof(int));
    int* row_ptr  = (int*)alloc((NN + 1) * sizeof(int));
    int* cursor   = (int*)alloc(NN * sizeof(int));
    int* esrc     = (int*)alloc(NE * sizeof(int));
    float* rs_out = (float*)alloc(NN * sizeof(float));
    float* rs_in  = (float*)alloc(NN * sizeof(float));
    float* bufA   = (float*)alloc((size_t)NN * H1 * sizeof(float));   // y1, then agg2
    float* bufB   = (float*)alloc((size_t)NN * H1 * sizeof(float));   // h_scaled, then mean|log_std
    _Float16* Zh  = (_Float16*)alloc((size_t)NN * H2 * sizeof(_Float16));

    k_zero<<<(NN + 255) / 256, 256, 0, stream>>>(degc_out, NN);
    k_zero<<<(NN + 255) / 256, 256, 0, stream>>>(degc_in, NN);
    k_count<<<(NE + 255) / 256, 256, 0, stream>>>(src, dst, degc_out, degc_in);
    k_scan<<<1, 1024, 0, stream>>>(degc_in, degc_out, row_ptr, cursor, rs_in, rs_out);
    k_bucket<<<(NE + 255) / 256, 256, 0, stream>>>(src, dst, row_ptr, cursor, esrc);

    // y1 = (features * rs_out) @ W1
    k_gemm<<<dim3((NN + 63) / 64, H1 / 64), 256, 0, stream>>>(
        features, FD, NN, FD, W1, nullptr, H1, H1, nullptr, nullptr, rs_out, bufA, H1);
    // h_scaled = relu(agg(y1)*rs_in + b1) * rs_out
    k_agg<true><<<NN / 4, 256, 0, stream>>>(bufA, bufB, esrc, row_ptr, rs_in, rs_out, b1);
    // agg2 = agg(h_scaled) * rs_in
    k_agg<false><<<NN / 4, 256, 0, stream>>>(bufB, bufA, esrc, row_ptr, rs_in, nullptr, nullptr);
    // [mean | log_std] = agg2 @ [W2|W3] + [b2|b3]
    k_gemm<<<dim3((NN + 63) / 64, 4), 256, 0, stream>>>(
        bufA, H1, NN, H1, W2, W3, H2, H2, b2, b3, nullptr, bufB, 256);
    k_z<<<(NN * H2 + 255) / 256, 256, 0, stream>>>(bufB, noise, Zh);
    k_decoder<<<dim3((NN + 127) / 128, (NN + 127) / 128), 256, 0, stream>>>(Zh, out);
}